// Round 4
// baseline (432.909 us; speedup 1.0000x reference)
//
#include <hip/hip_runtime.h>
#include <hip/hip_bf16.h>

#define N_NODES 2048
#define N_PAIRS 65536
#define DIM 512
#define NP 16
#define SLOTS 96          // max pairs per row (Poisson(32), observed max ~60)
#define SP 520            // LDS stride for 512-col prod tile
#define NCHUNKA (N_PAIRS/64)

typedef __attribute__((ext_vector_type(8))) short s16x8;
typedef __attribute__((ext_vector_type(8))) unsigned short u16x8;
typedef __attribute__((ext_vector_type(4))) float f32x4;

static __device__ __forceinline__ unsigned short f2bf(float x) {
    union { float f; unsigned int u; } v; v.f = x;
    unsigned int r = v.u + 0x7FFFu + ((v.u >> 16) & 1u);   // RNE
    return (unsigned short)(r >> 16);
}
static __device__ __forceinline__ float bf2f(unsigned short u) {
    union { unsigned int u; float f; } v; v.u = ((unsigned int)u) << 16;
    return v.f;
}
static __device__ __forceinline__ u16x8 pack8(float4 a, float4 b) {
    u16x8 r;
    r[0]=f2bf(a.x); r[1]=f2bf(a.y); r[2]=f2bf(a.z); r[3]=f2bf(a.w);
    r[4]=f2bf(b.x); r[5]=f2bf(b.y); r[6]=f2bf(b.z); r[7]=f2bf(b.w);
    return r;
}

// ---------------------------------------------------------------------------
// Kernel 1: fused dual GEMM via bf16 MFMA (unchanged from R3).
// ---------------------------------------------------------------------------
#define GBM 64
#define GBN 64
#define GBK 32
#define GSA 40

__global__ __launch_bounds__(256) void gemm_so(
    const float* __restrict__ A, const float* __restrict__ Ws, const float* __restrict__ bsv,
    const float* __restrict__ Wo, const float* __restrict__ bov,
    unsigned short* __restrict__ Sb, unsigned short* __restrict__ Ob)
{
    __shared__ unsigned short As[GBM*GSA];
    __shared__ unsigned short Bs[GBN*GSA];
    const int tid = threadIdx.x;
    const int m0 = blockIdx.y*GBM, n0 = blockIdx.x*GBN;
    const int ar = tid>>2, ac = (tid&3)*8;
    const float* Arow = A + (size_t)(m0+ar)*DIM + ac;
    const int nrow = n0 + ar;
    const float* Wrow = (nrow < DIM ? Ws + (size_t)nrow*DIM : Wo + (size_t)(nrow-DIM)*DIM) + ac;
    float4 a_r[2], b_r[2];
    a_r[0] = *(const float4*)(Arow);   a_r[1] = *(const float4*)(Arow+4);
    b_r[0] = *(const float4*)(Wrow);   b_r[1] = *(const float4*)(Wrow+4);

    const int lane = tid&63, wid = tid>>6;
    const int wm = (wid>>1)*32, wn = (wid&1)*32;
    const int fr = lane&15, ks8 = (lane>>4)*8;
    f32x4 acc[2][2] = {};
    for (int k0=0; k0<DIM; k0+=GBK) {
        *(u16x8*)&As[ar*GSA+ac] = pack8(a_r[0],a_r[1]);
        *(u16x8*)&Bs[ar*GSA+ac] = pack8(b_r[0],b_r[1]);
        __syncthreads();
        if (k0+GBK < DIM) {
            a_r[0] = *(const float4*)(Arow + k0+GBK);   a_r[1] = *(const float4*)(Arow + k0+GBK + 4);
            b_r[0] = *(const float4*)(Wrow + k0+GBK);   b_r[1] = *(const float4*)(Wrow + k0+GBK + 4);
        }
        s16x8 af[2], bfr[2];
        #pragma unroll
        for (int mi=0;mi<2;++mi) af[mi]  = *(const s16x8*)&As[(wm+mi*16+fr)*GSA + ks8];
        #pragma unroll
        for (int ni=0;ni<2;++ni) bfr[ni] = *(const s16x8*)&Bs[(wn+ni*16+fr)*GSA + ks8];
        #pragma unroll
        for (int mi=0;mi<2;++mi)
            #pragma unroll
            for (int ni=0;ni<2;++ni)
                acc[mi][ni] = __builtin_amdgcn_mfma_f32_16x16x32_bf16(af[mi], bfr[ni], acc[mi][ni], 0,0,0);
        __syncthreads();
    }
    const int rg = lane>>4;
    #pragma unroll
    for (int ni=0;ni<2;++ni) {
        const int n = n0 + wn + ni*16 + fr;
        const float bias = (n < DIM) ? bsv[n] : bov[n-DIM];
        unsigned short* dst = (n < DIM) ? (Sb + n) : (Ob + (n - DIM));
        #pragma unroll
        for (int mi=0;mi<2;++mi) {
            #pragma unroll
            for (int q=0;q<4;++q) {
                const int m = m0 + wm + mi*16 + rg*4 + q;
                dst[(size_t)m*DIM] = f2bf(acc[mi][ni][q] + bias);
            }
        }
    }
}

// ---------------------------------------------------------------------------
// Kernel 2: per-row expected pair counts (for consumer readiness).
// ---------------------------------------------------------------------------
__global__ __launch_bounds__(256) void hist_k(const int* __restrict__ idx, int* __restrict__ hist)
{
    int e = blockIdx.x * 256 + threadIdx.x;
    atomicAdd(&hist[idx[2*e]], 1);
}

// ---------------------------------------------------------------------------
// Kernel 3: fused producer-consumer persistent kernel.
// Phase A (ticketed): 64-pair chunks of MFMA pair projection, scatter to
//   per-row slots, release-increment rowdone[i].
// Phase B (ticketed): per-row softmax; acquire-spin until rowdone[r]==hist[r];
//   single-pass dense write via LDS col->slot map + per-slot prob rows.
// Deadlock-free: phase-A work is drained by ticket before any block idles in
// phase B; phase-B spins only on phase-A work owned by resident blocks.
// ---------------------------------------------------------------------------
__global__ __launch_bounds__(128) void fused_k(
    const unsigned short* __restrict__ Sb, const unsigned short* __restrict__ Ob,
    const float* __restrict__ U, const int* __restrict__ idx,
    const float* __restrict__ w_w, const float* __restrict__ w_b,
    int* __restrict__ rowcnt, int* __restrict__ rowdone, const int* __restrict__ hist,
    int* __restrict__ rowj, float* __restrict__ rowv,
    int* __restrict__ tickets, float* __restrict__ out)
{
    __shared__ __align__(16) unsigned char smem[2*16*SP*2];   // 33280 B
    __shared__ int tkA, tkB, ndv;
    __shared__ float mPv[NP], invZv[NP];

    const int tid = threadIdx.x;
    const int lane = tid & 63, wid = tid >> 6;
    const int fr = lane & 15, ks8 = (lane >> 4) * 8;

    // ---------------- phase A ----------------
    {
        s16x8 wreg[16];
        #pragma unroll
        for (int st=0;st<16;++st) {
            const float4* wp = (const float4*)(w_w + (size_t)fr*DIM + st*32 + ks8);
            u16x8 t = pack8(wp[0], wp[1]);
            wreg[st] = *(s16x8*)&t;
        }
        const float wbv = w_b[fr];
        unsigned short* P = (unsigned short*)smem;
        unsigned short* Pw = &P[wid*16*SP];
        for (;;) {
            __syncthreads();
            if (tid == 0) tkA = atomicAdd(&tickets[0], 1);
            __syncthreads();
            const int chunk = tkA;
            if (chunk >= NCHUNKA) break;
            const int eb = chunk*64 + wid*32;
            for (int it = 0; it < 2; ++it) {
                const int e0 = eb + it*16;
                #pragma unroll 4
                for (int s8=0; s8<16; ++s8) {
                    const int e = e0 + s8;
                    const int i = idx[2*e], j = idx[2*e+1];
                    u16x8 sv = *(const u16x8*)(Sb + (size_t)i*DIM + lane*8);
                    u16x8 ov = *(const u16x8*)(Ob + (size_t)j*DIM + lane*8);
                    const float4* up = (const float4*)(U + (size_t)e*DIM + lane*8);
                    float4 u0 = up[0], u1 = up[1];
                    float4 p0, p1;
                    p0.x = bf2f(sv[0])*bf2f(ov[0])*u0.x;
                    p0.y = bf2f(sv[1])*bf2f(ov[1])*u0.y;
                    p0.z = bf2f(sv[2])*bf2f(ov[2])*u0.z;
                    p0.w = bf2f(sv[3])*bf2f(ov[3])*u0.w;
                    p1.x = bf2f(sv[4])*bf2f(ov[4])*u1.x;
                    p1.y = bf2f(sv[5])*bf2f(ov[5])*u1.y;
                    p1.z = bf2f(sv[6])*bf2f(ov[6])*u1.z;
                    p1.w = bf2f(sv[7])*bf2f(ov[7])*u1.w;
                    *(u16x8*)&Pw[s8*SP + lane*8] = pack8(p0, p1);
                }
                f32x4 acc = {0.f,0.f,0.f,0.f};
                #pragma unroll
                for (int st=0;st<16;++st) {
                    s16x8 af = *(const s16x8*)&Pw[fr*SP + st*32 + ks8];
                    acc = __builtin_amdgcn_mfma_f32_16x16x32_bf16(af, wreg[st], acc, 0,0,0);
                }
                int iv = 0, posv = 0;
                if (lane < 16) {
                    const int e = e0 + lane;
                    iv = idx[2*e];
                    const int jv = idx[2*e + 1];
                    posv = atomicAdd(&rowcnt[iv], 1);
                    if (posv < SLOTS) rowj[iv*SLOTS + posv] = jv;
                }
                const int rg = lane>>4;
                #pragma unroll
                for (int q=0;q<4;++q) {
                    const int pr = rg*4 + q;
                    const int ip = __shfl(iv, pr, 64);
                    const int pp = __shfl(posv, pr, 64);
                    if (pp < SLOTS)
                        rowv[((size_t)ip*SLOTS + pp)*NP + fr] = acc[q] + wbv;
                }
                __threadfence();
                if (lane < 16)
                    __hip_atomic_fetch_add(&rowdone[iv], 1, __ATOMIC_RELEASE, __HIP_MEMORY_SCOPE_AGENT);
            }
        }
    }

    // ---------------- phase B ----------------
    float* vals = (float*)smem;                                 // [98][16] f32
    int*   jcol = (int*)(smem + 98*NP*4);                       // [96]
    unsigned char* deadf = (unsigned char*)(smem + 98*NP*4 + SLOTS*4);  // [96]
    unsigned char* cmap  = deadf + SLOTS;                       // [2048]
    float* red = (float*)(smem + 8800);                         // [8][17]

    for (;;) {
        __syncthreads();
        if (tid == 0) tkB = atomicAdd(&tickets[1], 1);
        __syncthreads();
        const int r = tkB;
        if (r >= N_NODES) break;
        const int expect = hist[r];
        {   // acquire-spin until row r fully produced (bounded guard)
            int g = 0;
            while (__hip_atomic_load(&rowdone[r], __ATOMIC_ACQUIRE, __HIP_MEMORY_SCOPE_AGENT) < expect
                   && g < (1<<25)) { ++g; __builtin_amdgcn_s_sleep(2); }
        }
        int c = expect; if (c > SLOTS) c = SLOTS;
        if (tid == 0) ndv = 0;
        for (int n = tid; n < N_NODES; n += 128) cmap[n] = (unsigned char)SLOTS;  // bg row
        for (int a = tid; a < c; a += 128) {
            jcol[a] = rowj[r*SLOTS + a];
            deadf[a] = 0;
            const float4* src = (const float4*)(rowv + ((size_t)r*SLOTS + a)*NP);
            float4* dst = (float4*)&vals[a*NP];
            dst[0]=src[0]; dst[1]=src[1]; dst[2]=src[2]; dst[3]=src[3];
        }
        __syncthreads();
        // merge duplicate columns into first occurrence
        for (int a = tid; a < c; a += 128) {
            int j = jcol[a]; int first = a;
            for (int b = 0; b < a; ++b) if (jcol[b] == j) { first = b; break; }
            if (first != a) {
                deadf[a] = 1;
                #pragma unroll
                for (int p = 0; p < NP; ++p) atomicAdd(&vals[first*NP+p], vals[a*NP+p]);
            }
        }
        __syncthreads();
        for (int a = tid; a < c; a += 128)
            if (!deadf[a] && jcol[a] != r) atomicAdd(&ndv, 1);
        __syncthreads();
        // stats: 8 chunks x 16 p
        const int p = tid & 15, ch = tid >> 4;
        float pm = 0.f;   // background logit 0 always present
        for (int a = ch; a < c; a += 8)
            if (!deadf[a] && jcol[a] != r) pm = fmaxf(pm, vals[a*NP+p]);
        red[ch*17+p] = pm;
        __syncthreads();
        if (tid < NP) {
            float m = 0.f;
            #pragma unroll
            for (int k = 0; k < 8; ++k) m = fmaxf(m, red[k*17+tid]);
            mPv[tid] = m;
        }
        __syncthreads();
        {
            const float m = mPv[p];
            float ps = 0.f;
            for (int a = ch; a < c; a += 8)
                if (!deadf[a] && jcol[a] != r) ps += __expf(vals[a*NP+p] - m);
            red[ch*17+p] = ps;
        }
        __syncthreads();
        if (tid < NP) {
            float zs = 0.f;
            #pragma unroll
            for (int k = 0; k < 8; ++k) zs += red[k*17+tid];
            const float m = mPv[tid];
            const float eb2 = __expf(-m);
            const float Z = zs + (float)(N_NODES - 1 - ndv) * eb2;
            const float iz = 1.0f / Z;
            invZv[tid] = iz;
            vals[SLOTS*NP + tid] = eb2 * iz;      // bg prob row (96)
            vals[(SLOTS+1)*NP + tid] = 0.f;       // zero row (97, diagonal)
        }
        __syncthreads();
        // probs in place + live column map
        for (int a = tid; a < c; a += 128) {
            if (!deadf[a] && jcol[a] != r) {
                #pragma unroll
                for (int p2 = 0; p2 < NP; ++p2)
                    vals[a*NP+p2] = __expf(vals[a*NP+p2] - mPv[p2]) * invZv[p2];
                cmap[jcol[a]] = (unsigned char)a;
            }
        }
        __syncthreads();
        if (tid == 0) cmap[r] = (unsigned char)(SLOTS+1);
        __syncthreads();
        // single-pass dense write: 8192 float4, 64 per thread
        float4* orow = (float4*)(out + (size_t)r * N_NODES * NP);
        const float4* v4 = (const float4*)vals;
        #pragma unroll 8
        for (int n = 0; n < 64; ++n) {
            const int i4 = tid + 128*n;
            const int col = i4 >> 2, q = i4 & 3;
            orow[i4] = v4[(int)cmap[col]*4 + q];
        }
    }
}

// ---------------------------------------------------------------------------
extern "C" void kernel_launch(void* const* d_in, const int* in_sizes, int n_in,
                              void* d_out, int out_size, void* d_ws, size_t ws_size,
                              hipStream_t stream)
{
    (void)in_sizes; (void)n_in; (void)out_size; (void)ws_size;
    const float* obj  = (const float*)d_in[0];
    const float* uni  = (const float*)d_in[1];
    const int*   idx  = (const int*)  d_in[2];
    const float* ws_w = (const float*)d_in[3];
    const float* ws_b = (const float*)d_in[4];
    const float* wo_w = (const float*)d_in[5];
    const float* wo_b = (const float*)d_in[6];
    const float* w_w  = (const float*)d_in[7];
    const float* w_b  = (const float*)d_in[8];
    float* out = (float*)d_out;

    unsigned short* Sb = (unsigned short*)d_ws;                     // 2 MB bf16
    unsigned short* Ob = Sb + (size_t)N_NODES * DIM;                // 2 MB bf16
    float* rowv  = (float*)(Ob + (size_t)N_NODES * DIM);            // 12.6 MB
    int* rowj    = (int*)(rowv + (size_t)N_NODES * SLOTS * NP);     // 768 KB
    int* rowcnt  = rowj + (size_t)N_NODES * SLOTS;
    int* rowdone = rowcnt + N_NODES;
    int* hist    = rowdone + N_NODES;
    int* tickets = hist + N_NODES;

    hipMemsetAsync(rowcnt, 0, (3 * N_NODES + 8) * sizeof(int), stream);
    hist_k<<<N_PAIRS/256, 256, 0, stream>>>(idx, hist);
    gemm_so<<<dim3(1024/GBN, N_NODES/GBM), 256, 0, stream>>>(obj, ws_w, ws_b, wo_w, wo_b, Sb, Ob);
    fused_k<<<1024, 128, 0, stream>>>(Sb, Ob, uni, idx, w_w, w_b,
                                      rowcnt, rowdone, hist, rowj, rowv, tickets, out);
}

// Round 5
// 149.208 us; speedup vs baseline: 2.9014x; 2.9014x over previous
//
#include <hip/hip_runtime.h>
#include <hip/hip_bf16.h>

#define N_NODES 2048
#define N_PAIRS 65536
#define DIM 512
#define NP 16
#define SLOTS 96   // max pairs per row (Poisson(32), observed max ~60)

typedef __attribute__((ext_vector_type(8))) short s16x8;
typedef __attribute__((ext_vector_type(8))) unsigned short u16x8;
typedef __attribute__((ext_vector_type(4))) float f32x4;

static __device__ __forceinline__ unsigned short f2bf(float x) {
    union { float f; unsigned int u; } v; v.f = x;
    unsigned int r = v.u + 0x7FFFu + ((v.u >> 16) & 1u);   // RNE
    return (unsigned short)(r >> 16);
}
static __device__ __forceinline__ float bf2f(unsigned short u) {
    union { unsigned int u; float f; } v; v.u = ((unsigned int)u) << 16;
    return v.f;
}
static __device__ __forceinline__ u16x8 pack8(float4 a, float4 b) {
    u16x8 r;
    r[0]=f2bf(a.x); r[1]=f2bf(a.y); r[2]=f2bf(a.z); r[3]=f2bf(a.w);
    r[4]=f2bf(b.x); r[5]=f2bf(b.y); r[6]=f2bf(b.z); r[7]=f2bf(b.w);
    return r;
}

// ---------------------------------------------------------------------------
// Kernel 1: fused dual GEMM via bf16 MFMA (unchanged from R3: 131 µs anchor).
// ---------------------------------------------------------------------------
#define GBM 64
#define GBN 64
#define GBK 32
#define GSA 40

__global__ __launch_bounds__(256) void gemm_so(
    const float* __restrict__ A, const float* __restrict__ Ws, const float* __restrict__ bsv,
    const float* __restrict__ Wo, const float* __restrict__ bov,
    unsigned short* __restrict__ Sb, unsigned short* __restrict__ Ob)
{
    __shared__ unsigned short As[GBM*GSA];
    __shared__ unsigned short Bs[GBN*GSA];
    const int tid = threadIdx.x;
    const int m0 = blockIdx.y*GBM, n0 = blockIdx.x*GBN;
    const int ar = tid>>2, ac = (tid&3)*8;
    const float* Arow = A + (size_t)(m0+ar)*DIM + ac;
    const int nrow = n0 + ar;
    const float* Wrow = (nrow < DIM ? Ws + (size_t)nrow*DIM : Wo + (size_t)(nrow-DIM)*DIM) + ac;
    float4 a_r[2], b_r[2];
    a_r[0] = *(const float4*)(Arow);   a_r[1] = *(const float4*)(Arow+4);
    b_r[0] = *(const float4*)(Wrow);   b_r[1] = *(const float4*)(Wrow+4);

    const int lane = tid&63, wid = tid>>6;
    const int wm = (wid>>1)*32, wn = (wid&1)*32;
    const int fr = lane&15, ks8 = (lane>>4)*8;
    f32x4 acc[2][2] = {};
    for (int k0=0; k0<DIM; k0+=GBK) {
        *(u16x8*)&As[ar*GSA+ac] = pack8(a_r[0],a_r[1]);
        *(u16x8*)&Bs[ar*GSA+ac] = pack8(b_r[0],b_r[1]);
        __syncthreads();
        if (k0+GBK < DIM) {
            a_r[0] = *(const float4*)(Arow + k0+GBK);   a_r[1] = *(const float4*)(Arow + k0+GBK + 4);
            b_r[0] = *(const float4*)(Wrow + k0+GBK);   b_r[1] = *(const float4*)(Wrow + k0+GBK + 4);
        }
        s16x8 af[2], bfr[2];
        #pragma unroll
        for (int mi=0;mi<2;++mi) af[mi]  = *(const s16x8*)&As[(wm+mi*16+fr)*GSA + ks8];
        #pragma unroll
        for (int ni=0;ni<2;++ni) bfr[ni] = *(const s16x8*)&Bs[(wn+ni*16+fr)*GSA + ks8];
        #pragma unroll
        for (int mi=0;mi<2;++mi)
            #pragma unroll
            for (int ni=0;ni<2;++ni)
                acc[mi][ni] = __builtin_amdgcn_mfma_f32_16x16x32_bf16(af[mi], bfr[ni], acc[mi][ni], 0,0,0);
        __syncthreads();
    }
    const int rg = lane>>4;
    #pragma unroll
    for (int ni=0;ni<2;++ni) {
        const int n = n0 + wn + ni*16 + fr;
        const float bias = (n < DIM) ? bsv[n] : bov[n-DIM];
        unsigned short* dst = (n < DIM) ? (Sb + n) : (Ob + (n - DIM));
        #pragma unroll
        for (int mi=0;mi<2;++mi) {
            #pragma unroll
            for (int q=0;q<4;++q) {
                const int m = m0 + wm + mi*16 + rg*4 + q;
                dst[(size_t)m*DIM] = f2bf(acc[mi][ni][q] + bias);
            }
        }
    }
}

// ---------------------------------------------------------------------------
// Kernel 2: pair projection, direct-fragment loads (no LDS at all).
// Wave handles 16 pairs; lane owns pair fr = lane&15, k-window ks8.
// Per k-chunk st: load s/o (bf16, 16B) + u (f32, 32B) for own pair,
// prod in registers -> bf16 frag -> MFMA vs wreg[st]. Scatter to row slots.
// ---------------------------------------------------------------------------
__global__ __launch_bounds__(256) void pairproj_k(
    const unsigned short* __restrict__ Sb, const unsigned short* __restrict__ Ob,
    const float* __restrict__ U, const int* __restrict__ idx,
    const float* __restrict__ w_w, const float* __restrict__ w_b,
    int* __restrict__ rowcnt, int* __restrict__ rowj, float* __restrict__ rowv)
{
    const int tid = threadIdx.x;
    const int lane = tid & 63, wid = tid >> 6;
    const int fr = lane & 15, ks8 = (lane >> 4) * 8;
    // B fragments: w_w[p=fr][st*32 + ks8 .. +7], resident all kernel (64 VGPR)
    s16x8 wreg[16];
    #pragma unroll
    for (int st = 0; st < 16; ++st) {
        const float4* wp = (const float4*)(w_w + (size_t)fr*DIM + st*32 + ks8);
        u16x8 t = pack8(wp[0], wp[1]);
        wreg[st] = *(s16x8*)&t;
    }
    const float wbv = w_b[fr];

    const int e = blockIdx.x * 64 + wid * 16 + fr;   // this lane's pair
    const int i = idx[2*e], j = idx[2*e + 1];
    const unsigned short* sp = Sb + (size_t)i * DIM;
    const unsigned short* op = Ob + (size_t)j * DIM;
    const float*          up = U  + (size_t)e * DIM;

    f32x4 acc = {0.f, 0.f, 0.f, 0.f};
    #pragma unroll 4
    for (int st = 0; st < 16; ++st) {
        const int k = st*32 + ks8;
        u16x8 sv = *(const u16x8*)(sp + k);
        u16x8 ov = *(const u16x8*)(op + k);
        float4 u0 = *(const float4*)(up + k);
        float4 u1 = *(const float4*)(up + k + 4);
        float4 p0, p1;
        p0.x = bf2f(sv[0])*bf2f(ov[0])*u0.x;
        p0.y = bf2f(sv[1])*bf2f(ov[1])*u0.y;
        p0.z = bf2f(sv[2])*bf2f(ov[2])*u0.z;
        p0.w = bf2f(sv[3])*bf2f(ov[3])*u0.w;
        p1.x = bf2f(sv[4])*bf2f(ov[4])*u1.x;
        p1.y = bf2f(sv[5])*bf2f(ov[5])*u1.y;
        p1.z = bf2f(sv[6])*bf2f(ov[6])*u1.z;
        p1.w = bf2f(sv[7])*bf2f(ov[7])*u1.w;
        u16x8 pa = pack8(p0, p1);
        acc = __builtin_amdgcn_mfma_f32_16x16x32_bf16(*(s16x8*)&pa, wreg[st], acc, 0,0,0);
    }
    // slot allocation on lanes 0..15 (they own distinct pairs), broadcast for write
    int posv = 0;
    if (lane < 16) {
        posv = atomicAdd(&rowcnt[i], 1);
        if (posv < SLOTS) rowj[i*SLOTS + posv] = j;
    }
    const int rg = lane >> 4;
    #pragma unroll
    for (int q = 0; q < 4; ++q) {
        const int pr = rg*4 + q;                    // pair row this lane writes
        const int ip = __shfl(i, pr, 64);
        const int pp = __shfl(posv, pr, 64);
        if (pp < SLOTS)
            rowv[((size_t)ip*SLOTS + pp)*NP + fr] = acc[q] + wbv;
    }
}

// ---------------------------------------------------------------------------
// Kernel 3: per-row sparse softmax, single-pass dense write via col->slot map.
// vals rows: [0..SLOTS) = per-slot probs, SLOTS = background, SLOTS+1 = zero.
// ---------------------------------------------------------------------------
__global__ __launch_bounds__(256) void softmax_k(
    const int* __restrict__ rowcnt, const int* __restrict__ rowj,
    const float* __restrict__ rowv, float* __restrict__ out)
{
    __shared__ __align__(16) float vals[(SLOTS+2)*NP];   // 6.1 KB
    __shared__ int jcol[SLOTS];
    __shared__ unsigned char deadf[SLOTS];
    __shared__ unsigned char cmap[N_NODES];              // 2 KB
    __shared__ float red[16][17];
    __shared__ float mPv[NP], invZv[NP];
    __shared__ int ndv;
    const int r = blockIdx.x;
    const int t = threadIdx.x;
    int c = rowcnt[r];
    if (c > SLOTS) c = SLOTS;

    if (t == 0) ndv = 0;
    for (int n = t; n < N_NODES; n += 256) cmap[n] = (unsigned char)SLOTS;  // bg
    for (int a = t; a < c; a += 256) {
        jcol[a] = rowj[r*SLOTS + a];
        deadf[a] = 0;
        const float4* src = (const float4*)(rowv + ((size_t)r*SLOTS + a)*NP);
        float4* dst = (float4*)&vals[a*NP];
        dst[0]=src[0]; dst[1]=src[1]; dst[2]=src[2]; dst[3]=src[3];
    }
    __syncthreads();

    // merge duplicate columns into first occurrence
    for (int a = t; a < c; a += 256) {
        int j = jcol[a]; int first = a;
        for (int b = 0; b < a; ++b) if (jcol[b] == j) { first = b; break; }
        if (first != a) {
            deadf[a] = 1;
            #pragma unroll
            for (int p = 0; p < NP; ++p) atomicAdd(&vals[first*NP+p], vals[a*NP+p]);
        }
    }
    __syncthreads();
    for (int a = t; a < c; a += 256)
        if (!deadf[a] && jcol[a] != r) atomicAdd(&ndv, 1);
    __syncthreads();

    // stats: 16 chunks x 16 p
    const int p = t & 15, ch = t >> 4;
    float pm = 0.f;   // background logit 0 always present
    for (int a = ch; a < c; a += 16)
        if (!deadf[a] && jcol[a] != r) pm = fmaxf(pm, vals[a*NP+p]);
    red[ch][p] = pm;
    __syncthreads();
    if (t < NP) {
        float m = 0.f;
        #pragma unroll
        for (int k = 0; k < 16; ++k) m = fmaxf(m, red[k][t]);
        mPv[t] = m;
    }
    __syncthreads();
    {
        const float m = mPv[p];
        float ps = 0.f;
        for (int a = ch; a < c; a += 16)
            if (!deadf[a] && jcol[a] != r) ps += __expf(vals[a*NP+p] - m);
        red[ch][p] = ps;
    }
    __syncthreads();
    if (t < NP) {
        float zs = 0.f;
        #pragma unroll
        for (int k = 0; k < 16; ++k) zs += red[k][t];
        const float m = mPv[t];
        const float eb = __expf(-m);
        const float Z = zs + (float)(N_NODES - 1 - ndv) * eb;
        const float iz = 1.0f / Z;
        invZv[t] = iz;
        vals[SLOTS*NP + t] = eb * iz;       // background prob row
        vals[(SLOTS+1)*NP + t] = 0.f;       // zero row (diagonal)
    }
    __syncthreads();

    // probs in place + live column map
    for (int a = t; a < c; a += 256) {
        if (!deadf[a] && jcol[a] != r) {
            #pragma unroll
            for (int p2 = 0; p2 < NP; ++p2)
                vals[a*NP+p2] = __expf(vals[a*NP+p2] - mPv[p2]) * invZv[p2];
            cmap[jcol[a]] = (unsigned char)a;
        }
    }
    __syncthreads();
    if (t == 0) cmap[r] = (unsigned char)(SLOTS+1);
    __syncthreads();

    // single-pass dense write: 8192 float4, 32 per thread
    float4* orow = (float4*)(out + (size_t)r * N_NODES * NP);
    const float4* v4 = (const float4*)vals;
    #pragma unroll 8
    for (int n = 0; n < 32; ++n) {
        const int i4 = t + 256*n;
        const int col = i4 >> 2, q = i4 & 3;
        orow[i4] = v4[(int)cmap[col]*4 + q];
    }
}

// ---------------------------------------------------------------------------
extern "C" void kernel_launch(void* const* d_in, const int* in_sizes, int n_in,
                              void* d_out, int out_size, void* d_ws, size_t ws_size,
                              hipStream_t stream)
{
    (void)in_sizes; (void)n_in; (void)out_size; (void)ws_size;
    const float* obj  = (const float*)d_in[0];
    const float* uni  = (const float*)d_in[1];
    const int*   idx  = (const int*)  d_in[2];
    const float* ws_w = (const float*)d_in[3];
    const float* ws_b = (const float*)d_in[4];
    const float* wo_w = (const float*)d_in[5];
    const float* wo_b = (const float*)d_in[6];
    const float* w_w  = (const float*)d_in[7];
    const float* w_b  = (const float*)d_in[8];
    float* out = (float*)d_out;

    unsigned short* Sb = (unsigned short*)d_ws;                     // 2 MB bf16
    unsigned short* Ob = Sb + (size_t)N_NODES * DIM;                // 2 MB bf16
    float* rowv  = (float*)(Ob + (size_t)N_NODES * DIM);            // 12.6 MB
    int* rowj    = (int*)(rowv + (size_t)N_NODES * SLOTS * NP);     // 768 KB
    int* rowcnt  = rowj + (size_t)N_NODES * SLOTS;                  // 8 KB

    hipMemsetAsync(rowcnt, 0, N_NODES * sizeof(int), stream);
    gemm_so<<<dim3(1024/GBN, N_NODES/GBM), 256, 0, stream>>>(obj, ws_w, ws_b, wo_w, wo_b, Sb, Ob);
    pairproj_k<<<N_PAIRS/64, 256, 0, stream>>>(Sb, Ob, uni, idx, w_w, w_b, rowcnt, rowj, rowv);
    softmax_k<<<N_NODES, 256, 0, stream>>>(rowcnt, rowj, rowv, out);
}